// Round 1
// baseline (511.417 us; speedup 1.0000x reference)
//
#include <hip/hip_runtime.h>
#include <hip/hip_bf16.h>
#include <cstdint>

// Problem constants (bsz=8, h=1024, seq=1024, K=2 taps)
#define HSZ   1024
#define SEQ   1024
#define NTOT  8192      // bsz*seq
#define K2    2048      // 2*h (i,tap interleaved)

typedef __attribute__((ext_vector_type(8))) short bf16x8;
typedef __attribute__((ext_vector_type(4))) float f32x4;

// counted waits: literal immediates (T4 — never drain vmcnt in the main loop)
#define WAITVM(N) asm volatile("s_waitcnt vmcnt(" #N ")" ::: "memory")
#define LGKM0     asm volatile("s_waitcnt lgkmcnt(0)" ::: "memory")

__device__ __forceinline__ unsigned f2bf(float x) {
  unsigned u = __builtin_bit_cast(unsigned, x);
  return (u + 0x7fffu + ((u >> 16) & 1u)) >> 16;   // RNE, inputs are finite
}
__device__ __forceinline__ float fsig(float x)  { return 1.f / (1.f + __expf(-x)); }
__device__ __forceinline__ float ftanh(float x) { return 1.f - 2.f / (__expf(2.f * x) + 1.f); }

__device__ __forceinline__ void gload_lds16(const void* g, void* l) {
  __builtin_amdgcn_global_load_lds(
      (const __attribute__((address_space(1))) unsigned*)g,
      (__attribute__((address_space(3))) unsigned*)l, 16, 0, 0);
}

// ---- prep 1: weight fp32 -> bf16, layout unchanged (o, k=2i+tap contiguous) ----
__global__ void conv_weight_kernel(const float* __restrict__ w, unsigned* __restrict__ wb) {
  int idx = (blockIdx.x * 256 + threadIdx.x) * 4;    // 8192 blocks * 1024 floats = exact
  f32x4 v = *(const f32x4*)(w + idx);
  uint2 o;
  o.x = f2bf(v.x) | (f2bf(v.y) << 16);
  o.y = f2bf(v.z) | (f2bf(v.w) << 16);
  *(uint2*)(wb + (idx >> 1)) = o;
}

// ---- prep 2: Bd[n][k] bf16, k=2i+tap: tap0 = x[t-1] (z0h at t=0), tap1 = x[t] ----
__global__ void build_bdup_kernel(const float* __restrict__ z1ss, const float* __restrict__ z0,
                                  unsigned* __restrict__ bd) {
  __shared__ float tile[32 * 34];                    // [ii][j], j in [0,33) = t0-1..t0+31
  const int tid = threadIdx.x;
  const int n0 = blockIdx.x * 32;                    // 256 n-tiles (never cross batch)
  const int i0 = blockIdx.y * 32;                    // 32 i-tiles
  const int b  = n0 >> 10;
  const int t0 = n0 & 1023;
  const int ii = tid >> 3, js = tid & 7;
  const float* zrow = z1ss + (b * 2048 + i0 + ii) * 1024;
  const float z0v = z0[b * 2048 + i0 + ii];
#pragma unroll
  for (int p = 0; p < 5; ++p) {
    int j = js + p * 8;
    if (j < 33) {
      int gt = t0 - 1 + j;
      tile[ii * 34 + j] = (gt < 0) ? z0v : zrow[gt];
    }
  }
  __syncthreads();
  const int i2 = tid & 31, ts = tid >> 5;
#pragma unroll
  for (int p = 0; p < 4; ++p) {
    int tt = ts + p * 8;
    float prev = tile[i2 * 34 + tt];                 // x[t-1] (or z0h)
    float cur  = tile[i2 * 34 + tt + 1];             // x[t]
    bd[(n0 + tt) * 1024 + i0 + i2] = f2bf(prev) | (f2bf(cur) << 16);  // shorts 2i / 2i+1
  }
}

// =====================================================================
// 256x256 GEMM, BK=32, 8 waves (2m x 4n), 4 LDS K-tile buffers (128 KiB),
// 8-phase-style schedule: per phase {2x global_load_lds (tile T+3) ||
// ds_read frags || barrier; lgkmcnt(0); setprio(1); 16 MFMA; setprio(0);
// barrier}. One counted vmcnt(8) per K-tile — loads stay in flight across
// barriers (T3+T4). Slot-XOR LDS swizzle (measured conflict-free) with
// linear global_load_lds dest + pre-swizzled global source.
// Block rows = 4 gates x 64 channels; wave wm owns all 4 gates of 32
// channels -> fused LSTM epilogue is register-local per thread.
// =====================================================================
template<int BUF, int VMN, bool STG>
__device__ __forceinline__ void tile_step(
    unsigned short* __restrict__ ldsA, unsigned short* __restrict__ ldsB,
    const unsigned short*& aG0, const unsigned short*& aG1,
    const unsigned short*& bG0, const unsigned short*& bG1,
    const int sA0, const int sA1, const int aread, const int bread,
    f32x4 (&acc)[8][4])
{
  constexpr int SB = (BUF + 3) & 3;                  // stage dest buffer (tile T+3)
  const unsigned short* Ab = ldsA + BUF * 8192 + aread;
  const unsigned short* Bb = ldsB + BUF * 8192 + bread;
  bf16x8 afr[4], bfr[4];

  // ---------- phase 0: quadrant m0-3 x n0-3 ----------
  if constexpr (STG) {
    gload_lds16(aG0, ldsA + SB * 8192 + sA0);
    gload_lds16(bG0, ldsB + SB * 8192 + sA0);
  }
#pragma unroll
  for (int nt = 0; nt < 4; ++nt) bfr[nt] = *(const bf16x8*)(Bb + nt * 512);
#pragma unroll
  for (int m = 0; m < 4; ++m)    afr[m]  = *(const bf16x8*)(Ab + m * 512);
  __builtin_amdgcn_s_barrier();
  LGKM0;
  __builtin_amdgcn_sched_barrier(0);
  __builtin_amdgcn_s_setprio(1);
#pragma unroll
  for (int m = 0; m < 4; ++m)
#pragma unroll
    for (int nt = 0; nt < 4; ++nt)
      acc[m][nt] = __builtin_amdgcn_mfma_f32_16x16x32_bf16(afr[m], bfr[nt], acc[m][nt], 0, 0, 0);
  __builtin_amdgcn_s_setprio(0);
  __builtin_amdgcn_s_barrier();

  // ---------- phase 1: quadrant m4-7 x n0-3 (reuse bfr) ----------
  if constexpr (STG) {
    gload_lds16(aG1, ldsA + SB * 8192 + sA1);
    gload_lds16(bG1, ldsB + SB * 8192 + sA1);
    aG0 += 32; aG1 += 32; bG0 += 32; bG1 += 32;      // advance one K-tile
  }
#pragma unroll
  for (int m = 0; m < 4; ++m) afr[m] = *(const bf16x8*)(Ab + (m + 4) * 512);
  // validate next tile's buffer ONCE per K-tile: tiles T+2,T+3 stay in flight
  if constexpr (VMN == 8)      WAITVM(8);
  else if constexpr (VMN == 4) WAITVM(4);
  else if constexpr (VMN == 0) WAITVM(0);
  __builtin_amdgcn_s_barrier();
  LGKM0;
  __builtin_amdgcn_sched_barrier(0);
  __builtin_amdgcn_s_setprio(1);
#pragma unroll
  for (int m = 0; m < 4; ++m)
#pragma unroll
    for (int nt = 0; nt < 4; ++nt)
      acc[m + 4][nt] = __builtin_amdgcn_mfma_f32_16x16x32_bf16(afr[m], bfr[nt], acc[m + 4][nt], 0, 0, 0);
  __builtin_amdgcn_s_setprio(0);
  __builtin_amdgcn_s_barrier();
}

__launch_bounds__(512, 2)
__global__ void lstm_gemm_kernel(const unsigned short* __restrict__ Wb,
                                 const unsigned short* __restrict__ Bd,
                                 const float* __restrict__ uss,
                                 const float* __restrict__ z1ss,
                                 const float* __restrict__ z0,
                                 const float* __restrict__ bias,
                                 float* __restrict__ out) {
  __shared__ unsigned short ldsA[4 * 8192];          // 4 bufs x 256 rows x 32 k (64 KiB)
  __shared__ unsigned short ldsB[4 * 8192];          // 64 KiB
  const int tid  = threadIdx.x;
  const int w    = tid >> 6, lane = tid & 63;
  const int l15  = lane & 15, quad = lane >> 4;
  const int wm   = w >> 2, wn = w & 3;               // 2 x 4 wave grid

  // bijective XCD swizzle over 512 wgs; per-XCD chunk = 16 c-tiles x 4 n-tiles
  const int bid = blockIdx.x;
  const int wg  = (bid & 7) * 64 + (bid >> 3);
  const int c0  = (wg & 15) * 64;                    // channel tile (64 ch x 4 gates)
  const int n0  = (wg >> 4) * 256;                   // n tile (stays inside one batch)

  // ---- staging descriptors: unit u=(w*2+j)*64+lane; row=u>>2, slot=u&3;
  // global chunk = slot ^ ((row>>1)&3)  (slot-XOR swizzle, conflict-free reads)
  const int sA0 = (w * 2 + 0) * 512;                 // LDS ushort offset of load j=0
  const int sA1 = (w * 2 + 1) * 512;
  const unsigned short *aG0, *aG1, *bG0, *bG1;
  {
    const int u0 = (w * 2 + 0) * 64 + lane;
    const int r0 = u0 >> 2;
    const int k0c = ((u0 & 3) ^ ((r0 >> 1) & 3)) * 8;
    const int wr0 = ((r0 >> 5) & 3) * 1024 + c0 + (r0 >> 7) * 32 + (r0 & 31);
    aG0 = Wb + (size_t)wr0 * K2 + k0c;
    bG0 = Bd + (size_t)(n0 + r0) * K2 + k0c;
    const int u1 = (w * 2 + 1) * 64 + lane;
    const int r1 = u1 >> 2;
    const int k1c = ((u1 & 3) ^ ((r1 >> 1) & 3)) * 8;
    const int wr1 = ((r1 >> 5) & 3) * 1024 + c0 + (r1 >> 7) * 32 + (r1 & 31);
    aG1 = Wb + (size_t)wr1 * K2 + k1c;
    bG1 = Bd + (size_t)(n0 + r1) * K2 + k1c;
  }

  // fragment read offsets (shorts): row l15, swizzled chunk slot
  const int swz   = (l15 >> 1) & 3;
  const int lofs  = l15 * 32 + ((quad ^ swz) << 3);
  const int aread = wm * 4096 + lofs;                // wave's 128-row A half
  const int bread = wn * 2048 + lofs;                // wave's 64-row B slice

  f32x4 acc[8][4];
#pragma unroll
  for (int m = 0; m < 8; ++m)
#pragma unroll
    for (int nt = 0; nt < 4; ++nt)
      acc[m][nt] = (f32x4){0.f, 0.f, 0.f, 0.f};

  // ---- prologue: stage K-tiles 0,1,2 (3-ahead pipeline depth) ----
#pragma unroll
  for (int t = 0; t < 3; ++t) {
    gload_lds16(aG0 + t * 32, ldsA + t * 8192 + sA0);
    gload_lds16(aG1 + t * 32, ldsA + t * 8192 + sA1);
    gload_lds16(bG0 + t * 32, ldsB + t * 8192 + sA0);
    gload_lds16(bG1 + t * 32, ldsB + t * 8192 + sA1);
  }
  aG0 += 96; aG1 += 96; bG0 += 96; bG1 += 96;        // now at tile 3
  WAITVM(8);                                         // tile 0 resident (1,2 in flight)
  __builtin_amdgcn_s_barrier();

  // ---- main loop: 64 K-tiles, unrolled x4 so buffer indices are constants ----
  for (int it = 0; it < 15; ++it) {                  // T = 0..59
    tile_step<0, 8, true>(ldsA, ldsB, aG0, aG1, bG0, bG1, sA0, sA1, aread, bread, acc);
    tile_step<1, 8, true>(ldsA, ldsB, aG0, aG1, bG0, bG1, sA0, sA1, aread, bread, acc);
    tile_step<2, 8, true>(ldsA, ldsB, aG0, aG1, bG0, bG1, sA0, sA1, aread, bread, acc);
    tile_step<3, 8, true>(ldsA, ldsB, aG0, aG1, bG0, bG1, sA0, sA1, aread, bread, acc);
  }
  tile_step<0, 8, true >(ldsA, ldsB, aG0, aG1, bG0, bG1, sA0, sA1, aread, bread, acc); // T=60 (stages 63)
  tile_step<1, 4, false>(ldsA, ldsB, aG0, aG1, bG0, bG1, sA0, sA1, aread, bread, acc); // T=61
  tile_step<2, 0, false>(ldsA, ldsB, aG0, aG1, bG0, bG1, sA0, sA1, aread, bread, acc); // T=62
  tile_step<3, -1, false>(ldsA, ldsB, aG0, aG1, bG0, bG1, sA0, sA1, aread, bread, acc); // T=63

  // ---- fused LSTM epilogue ----
  // C/D: col=l15 (n), row=quad*4+reg (weight dim). Wave rows rr=m*16+quad*4+reg:
  // gate = m>>1, channel = c0 + wm*32 + (m&1)*16 + quad*4 + reg -> acc[g*2+cp].
  const int nbase = n0 + wn * 64 + l15;
#pragma unroll
  for (int nt = 0; nt < 4; ++nt) {
    const int n = nbase + nt * 16;
    const int b = n >> 10, t = n & 1023;
    const float* ussb = uss + (size_t)b * 4194304 + t;
    const int zoff = b * 2048 + 1024;
#pragma unroll
    for (int cp = 0; cp < 2; ++cp) {
#pragma unroll
      for (int r = 0; r < 4; ++r) {
        const int ch = c0 + wm * 32 + cp * 16 + quad * 4 + r;
        float p0 = acc[0 + cp][nt][r] + ussb[(size_t)ch * 1024]          + bias[ch];
        float p1 = acc[2 + cp][nt][r] + ussb[(size_t)(1024 + ch) * 1024] + bias[1024 + ch];
        float p2 = acc[4 + cp][nt][r] + ussb[(size_t)(2048 + ch) * 1024] + bias[2048 + ch];
        float p3 = acc[6 + cp][nt][r] + ussb[(size_t)(3072 + ch) * 1024] + bias[3072 + ch];
        float it = fsig(p0), ot = fsig(p1), g_ = ftanh(p2), ft = fsig(p3);
        float zc = t ? z1ss[(size_t)(zoff + ch) * 1024 + t - 1]
                     : z0[zoff + ch];
        float ct = ft * zc + it * g_;
        float ht = ot * ftanh(ct);
        float* ob = out + (size_t)(b * 2048 + ch) * 1024 + t;
        ob[0] = ht;
        ob[1048576] = ct;
      }
    }
  }
}

// ---- slow-but-correct fallback if ws too small ----
__global__ void naive_kernel(const float* __restrict__ z1ss, const float* __restrict__ uss,
                             const float* __restrict__ z0, const float* __restrict__ w,
                             const float* __restrict__ bias, float* __restrict__ out) {
  int idx = blockIdx.x * 256 + threadIdx.x;          // (b,c,t)
  int b = idx >> 20, c = (idx >> 10) & 1023, t = idx & 1023;
  float s0 = 0.f, s1 = 0.f, s2 = 0.f, s3 = 0.f;
  const float* xb = z1ss + b * 2097152;
  for (int i = 0; i < 1024; ++i) {
    float cur  = xb[i * 1024 + t];
    float prev = t ? xb[i * 1024 + t - 1] : z0[b * 2048 + i];
    const float* wr = w + c * 2048 + i * 2;
    s0 += wr[0]       * prev + wr[1]       * cur;
    s1 += wr[2097152] * prev + wr[2097153] * cur;
    s2 += wr[4194304] * prev + wr[4194305] * cur;
    s3 += wr[6291456] * prev + wr[6291457] * cur;
  }
  int ub = b * 4194304 + c * 1024 + t;
  float p0 = s0 + uss[ub]           + bias[c];
  float p1 = s1 + uss[ub + 1048576] + bias[1024 + c];
  float p2 = s2 + uss[ub + 2097152] + bias[2048 + c];
  float p3 = s3 + uss[ub + 3145728] + bias[3072 + c];
  float it = fsig(p0), ot = fsig(p1), g_ = ftanh(p2), ft = fsig(p3);
  float zc = t ? z1ss[(b * 2048 + 1024 + c) * 1024 + t - 1] : z0[b * 2048 + 1024 + c];
  float ct = ft * zc + it * g_;
  float ht = ot * ftanh(ct);
  int ob = (b * 2048 + c) * 1024 + t;
  out[ob] = ht;
  out[ob + 1048576] = ct;
}

extern "C" void kernel_launch(void* const* d_in, const int* in_sizes, int n_in,
                              void* d_out, int out_size, void* d_ws, size_t ws_size,
                              hipStream_t stream) {
  const float* z1ss = (const float*)d_in[0];
  const float* uss  = (const float*)d_in[1];
  const float* z0   = (const float*)d_in[2];
  const float* w    = (const float*)d_in[3];
  const float* bias = (const float*)d_in[4];
  float* out = (float*)d_out;

  const size_t needWb = (size_t)4096 * 2048 * 2;   // 16 MB bf16 weight
  const size_t needBd = (size_t)NTOT * K2 * 2;     // 32 MB bf16 B matrix
  if (ws_size >= needWb + needBd) {
    unsigned short* Wb = (unsigned short*)d_ws;
    unsigned short* Bd = Wb + (size_t)4096 * 2048;
    conv_weight_kernel<<<8192, 256, 0, stream>>>(w, (unsigned*)Wb);
    build_bdup_kernel<<<dim3(256, 32), 256, 0, stream>>>(z1ss, z0, (unsigned*)Bd);
    lstm_gemm_kernel<<<dim3(512), dim3(512), 0, stream>>>(Wb, Bd, uss, z1ss, z0, bias, out);
  } else {
    naive_kernel<<<32768, 256, 0, stream>>>(z1ss, uss, z0, w, bias, out);
  }
}

// Round 3
// 414.835 us; speedup vs baseline: 1.2328x; 1.2328x over previous
//
#include <hip/hip_runtime.h>
#include <hip/hip_bf16.h>
#include <cstdint>

// Problem constants (bsz=8, h=1024, seq=1024, K=2 taps)
#define HSZ   1024
#define SEQ   1024
#define NTOT  8192      // bsz*seq
#define K2    2048      // 2*h (i,tap interleaved)

typedef __attribute__((ext_vector_type(8))) short bf16x8;
typedef __attribute__((ext_vector_type(4))) float f32x4;

__device__ __forceinline__ unsigned f2bf(float x) {
  unsigned u = __builtin_bit_cast(unsigned, x);
  return (u + 0x7fffu + ((u >> 16) & 1u)) >> 16;   // RNE, inputs are finite
}
__device__ __forceinline__ float fsig(float x)  { return 1.f / (1.f + __expf(-x)); }
__device__ __forceinline__ float ftanh(float x) { return 1.f - 2.f / (__expf(2.f * x) + 1.f); }

__device__ __forceinline__ void gload_lds16(const void* g, void* l) {
  __builtin_amdgcn_global_load_lds(
      (const __attribute__((address_space(1))) unsigned*)g,
      (__attribute__((address_space(3))) unsigned*)l, 16, 0, 0);
}

// ---- prep 1: weight fp32 -> bf16, layout unchanged (o, k=2i+tap contiguous) ----
__global__ void conv_weight_kernel(const float* __restrict__ w, unsigned* __restrict__ wb) {
  int idx = (blockIdx.x * 256 + threadIdx.x) * 4;    // 8192 blocks * 1024 floats = exact
  f32x4 v = *(const f32x4*)(w + idx);
  uint2 o;
  o.x = f2bf(v.x) | (f2bf(v.y) << 16);
  o.y = f2bf(v.z) | (f2bf(v.w) << 16);
  *(uint2*)(wb + (idx >> 1)) = o;
}

// ---- prep 2: Bd[n][k] bf16, k=2i+tap: tap0 = x[t-1] (z0h at t=0), tap1 = x[t] ----
__global__ void build_bdup_kernel(const float* __restrict__ z1ss, const float* __restrict__ z0,
                                  unsigned* __restrict__ bd) {
  __shared__ float tile[32 * 34];                    // [ii][j], j in [0,33) = t0-1..t0+31
  const int tid = threadIdx.x;
  const int n0 = blockIdx.x * 32;                    // 256 n-tiles (never cross batch)
  const int i0 = blockIdx.y * 32;                    // 32 i-tiles
  const int b  = n0 >> 10;
  const int t0 = n0 & 1023;
  const int ii = tid >> 3, js = tid & 7;
  const float* zrow = z1ss + (b * 2048 + i0 + ii) * 1024;
  const float z0v = z0[b * 2048 + i0 + ii];
#pragma unroll
  for (int p = 0; p < 5; ++p) {
    int j = js + p * 8;
    if (j < 33) {
      int gt = t0 - 1 + j;
      tile[ii * 34 + j] = (gt < 0) ? z0v : zrow[gt];
    }
  }
  __syncthreads();
  const int i2 = tid & 31, ts = tid >> 5;
#pragma unroll
  for (int p = 0; p < 4; ++p) {
    int tt = ts + p * 8;
    float prev = tile[i2 * 34 + tt];                 // x[t-1] (or z0h)
    float cur  = tile[i2 * 34 + tt + 1];             // x[t]
    bd[(n0 + tt) * 1024 + i0 + i2] = f2bf(prev) | (f2bf(cur) << 16);  // shorts 2i / 2i+1
  }
}

// ---- GEMM + fused LSTM epilogue ----
// Proven m97-style 128x128 structure (237 us at BK=32), single change: BK=64.
// Halves the per-block __syncthreads/vmcnt(0)-drain count (128 -> 64) while
// keeping per-K ds_read/MFMA density and the 3-blocks/CU overlap that makes
// this structure stall-tolerant (m114). LDS 32 KB/block -> 96 KB at 3 blocks.
// Block: 128 A-rows (row = g*32+cc -> weight row g*1024+c0+cc) x 128 n-cols.
// Wave owns all 128 rows x 32 cols: acc[4][2][2] f32x4 = 64 regs/lane.
// LDS layout (A and B): row-major [128 rows][8 slots of 8 shorts],
//   slot = chunk ^ (row&7)  -> DMA-linear AND ds_read_b128 conflict-free
//   (per quarter-wave: 8 distinct slots -> all 32 banks, 2-way = free, m136).
__launch_bounds__(256, 3)
__global__ void lstm_gemm_kernel(const unsigned short* __restrict__ Wb,
                                 const unsigned short* __restrict__ Bd,
                                 const float* __restrict__ uss,
                                 const float* __restrict__ z1ss,
                                 const float* __restrict__ z0,
                                 const float* __restrict__ bias,
                                 float* __restrict__ out) {
  __shared__ unsigned short Asm_[128 * 64];   // 16 KB, swizzled
  __shared__ unsigned short Bsm_[128 * 64];   // 16 KB, swizzled
  const int tid  = threadIdx.x;
  const int wave = tid >> 6, lane = tid & 63;
  const int l15  = lane & 15, quad = lane >> 4;
  const int c0 = blockIdx.y * 32;
  const int n0 = blockIdx.x * 128;

  // staging: per wave 4 A-insts + 4 B-insts, each covers 8 rows x 64k (1 KiB LDS)
  const unsigned short* agp[4];
  const unsigned short* bgp[4];
#pragma unroll
  for (int j = 0; j < 4; ++j) {
    const int idx = (wave * 4 + j) * 64 + lane;      // lds 16B-unit index in [0,1024)
    const int row = idx >> 3;                        // [0,128)
    const int chunk = (idx & 7) ^ (row & 7);         // global k-chunk this lane fetches
    const int wrow = (row >> 5) * 1024 + c0 + (row & 31);
    agp[j] = Wb + (size_t)wrow * K2 + chunk * 8;
    bgp[j] = Bd + (size_t)(n0 + row) * K2 + chunk * 8;
  }
  unsigned short* ldsA[4];
  unsigned short* ldsB[4];
#pragma unroll
  for (int j = 0; j < 4; ++j) {
    ldsA[j] = Asm_ + (wave * 4 + j) * 512;
    ldsB[j] = Bsm_ + (wave * 4 + j) * 512;
  }

  // fragment read offset builder: row r in [0,128), k-half kh, lane quad:
  // shorts addr = r*64 + (((kh*4+quad) ^ (r&7)) << 3); r&7 == l15&7 for all frags.
  const int sw7 = l15 & 7;

  f32x4 acc[4][2][2];
#pragma unroll
  for (int g = 0; g < 4; ++g)
#pragma unroll
    for (int h = 0; h < 2; ++h)
#pragma unroll
      for (int nt = 0; nt < 2; ++nt)
        acc[g][h][nt] = (f32x4){0.f, 0.f, 0.f, 0.f};

  for (int k0 = 0; k0 < K2; k0 += 64) {
#pragma unroll
    for (int j = 0; j < 4; ++j) gload_lds16(agp[j] + k0, ldsA[j]);
#pragma unroll
    for (int j = 0; j < 4; ++j) gload_lds16(bgp[j] + k0, ldsB[j]);
    __syncthreads();                                  // drains vmcnt + barrier

#pragma unroll
    for (int kh = 0; kh < 2; ++kh) {
      const int slot = ((kh * 4 + quad) ^ sw7) << 3;  // shorts offset of 16B chunk
      bf16x8 bf[2];
#pragma unroll
      for (int nt = 0; nt < 2; ++nt) {
        const int br = wave * 32 + nt * 16 + l15;
        bf[nt] = *(const bf16x8*)(Bsm_ + br * 64 + slot);
      }
#pragma unroll
      for (int g = 0; g < 4; ++g)
#pragma unroll
        for (int h = 0; h < 2; ++h) {
          const int ar = (g * 2 + h) * 16 + l15;
          bf16x8 af = *(const bf16x8*)(Asm_ + ar * 64 + slot);
#pragma unroll
          for (int nt = 0; nt < 2; ++nt)
            acc[g][h][nt] = __builtin_amdgcn_mfma_f32_16x16x32_bf16(af, bf[nt], acc[g][h][nt], 0, 0, 0);
        }
    }
    __syncthreads();                                  // protect LDS before next stage
  }

  // epilogue: C/D layout col=lane&15 (n), row=quad*4+reg (m); all 4 gates register-local
#pragma unroll
  for (int h = 0; h < 2; ++h) {
#pragma unroll
    for (int r = 0; r < 4; ++r) {
      const int c = c0 + h * 16 + quad * 4 + r;
      const float bv0 = bias[c], bv1 = bias[1024 + c], bv2 = bias[2048 + c], bv3 = bias[3072 + c];
#pragma unroll
      for (int nt = 0; nt < 2; ++nt) {
        const int n = n0 + wave * 32 + nt * 16 + l15;
        const int b = n >> 10, t = n & 1023;
        const int ub = b * 4194304 + c * 1024 + t;   // uss[b][g*1024+c][t], gate stride 1048576
        float p0 = acc[0][h][nt][r] + uss[ub]           + bv0;
        float p1 = acc[1][h][nt][r] + uss[ub + 1048576] + bv1;
        float p2 = acc[2][h][nt][r] + uss[ub + 2097152] + bv2;
        float p3 = acc[3][h][nt][r] + uss[ub + 3145728] + bv3;
        float it = fsig(p0), ot = fsig(p1), g_ = ftanh(p2), ft = fsig(p3);
        float zc = t ? z1ss[(b * 2048 + 1024 + c) * 1024 + t - 1]
                     : z0[b * 2048 + 1024 + c];
        float ct = ft * zc + it * g_;
        float ht = ot * ftanh(ct);
        const int ob = (b * 2048 + c) * 1024 + t;
        out[ob] = ht;
        out[ob + 1048576] = ct;
      }
    }
  }
}

// ---- slow-but-correct fallback if ws too small ----
__global__ void naive_kernel(const float* __restrict__ z1ss, const float* __restrict__ uss,
                             const float* __restrict__ z0, const float* __restrict__ w,
                             const float* __restrict__ bias, float* __restrict__ out) {
  int idx = blockIdx.x * 256 + threadIdx.x;          // (b,c,t)
  int b = idx >> 20, c = (idx >> 10) & 1023, t = idx & 1023;
  float s0 = 0.f, s1 = 0.f, s2 = 0.f, s3 = 0.f;
  const float* xb = z1ss + b * 2097152;
  for (int i = 0; i < 1024; ++i) {
    float cur  = xb[i * 1024 + t];
    float prev = t ? xb[i * 1024 + t - 1] : z0[b * 2048 + i];
    const float* wr = w + c * 2048 + i * 2;
    s0 += wr[0]       * prev + wr[1]       * cur;
    s1 += wr[2097152] * prev + wr[2097153] * cur;
    s2 += wr[4194304] * prev + wr[4194305] * cur;
    s3 += wr[6291456] * prev + wr[6291457] * cur;
  }
  int ub = b * 4194304 + c * 1024 + t;
  float p0 = s0 + uss[ub]           + bias[c];
  float p1 = s1 + uss[ub + 1048576] + bias[1024 + c];
  float p2 = s2 + uss[ub + 2097152] + bias[2048 + c];
  float p3 = s3 + uss[ub + 3145728] + bias[3072 + c];
  float it = fsig(p0), ot = fsig(p1), g_ = ftanh(p2), ft = fsig(p3);
  float zc = t ? z1ss[(b * 2048 + 1024 + c) * 1024 + t - 1] : z0[b * 2048 + 1024 + c];
  float ct = ft * zc + it * g_;
  float ht = ot * ftanh(ct);
  int ob = (b * 2048 + c) * 1024 + t;
  out[ob] = ht;
  out[ob + 1048576] = ct;
}

extern "C" void kernel_launch(void* const* d_in, const int* in_sizes, int n_in,
                              void* d_out, int out_size, void* d_ws, size_t ws_size,
                              hipStream_t stream) {
  const float* z1ss = (const float*)d_in[0];
  const float* uss  = (const float*)d_in[1];
  const float* z0   = (const float*)d_in[2];
  const float* w    = (const float*)d_in[3];
  const float* bias = (const float*)d_in[4];
  float* out = (float*)d_out;

  const size_t needWb = (size_t)4096 * 2048 * 2;   // 16 MB bf16 weight
  const size_t needBd = (size_t)NTOT * K2 * 2;     // 32 MB bf16 B matrix
  if (ws_size >= needWb + needBd) {
    unsigned short* Wb = (unsigned short*)d_ws;
    unsigned short* Bd = Wb + (size_t)4096 * 2048;
    conv_weight_kernel<<<8192, 256, 0, stream>>>(w, (unsigned*)Wb);
    build_bdup_kernel<<<dim3(256, 32), 256, 0, stream>>>(z1ss, z0, (unsigned*)Bd);
    lstm_gemm_kernel<<<dim3(64, 32), 256, 0, stream>>>(Wb, Bd, uss, z1ss, z0, bias, out);
  } else {
    naive_kernel<<<32768, 256, 0, stream>>>(z1ss, uss, z0, w, bias, out);
  }
}